// Round 10
// baseline (273.569 us; speedup 1.0000x reference)
//
#include <hip/hip_runtime.h>
#include <cstdint>
#include <cstddef>

// Problem constants: N=4, C=D=256, H=W=64, L=4096
#define NB 4
#define CH 256
#define LL 4096

typedef unsigned short u16;
typedef unsigned int u32;
typedef unsigned char u8;
typedef __attribute__((ext_vector_type(8))) short bf16x8;
typedef __attribute__((ext_vector_type(4))) float f32x4;
typedef __attribute__((ext_vector_type(16))) float f32x16;

#define GPTR(p) ((const __attribute__((address_space(1))) u32*)(p))
#define LPTR(p) ((__attribute__((address_space(3))) u32*)(p))

__device__ __forceinline__ float blo(u32 x) { return __uint_as_float(x << 16); }
__device__ __forceinline__ float bhi(u32 x) { return __uint_as_float(x & 0xffff0000u); }
__device__ __forceinline__ float b2f(u16 h) { return __uint_as_float(((u32)h) << 16); }
__device__ __forceinline__ u16 f2b(float f) {
    u32 u = __float_as_uint(f);
    u32 r = (u + 0x7fffu + ((u >> 16) & 1u)) >> 16;  // RNE
    return (u16)r;
}
__device__ __forceinline__ u32 pack2(float a, float b) {
    return (u32)f2b(a) | ((u32)f2b(b) << 16);
}

// ---------------------------------------------------------------------------
// Kernel P: fused castw + tcast (R16, kept).
// ids [0,1024): tcast 64x64 tile; ids [1024,1280): castw + stats zero.
// ---------------------------------------------------------------------------
__global__ __launch_bounds__(256) void prep_kernel(
    const float* __restrict__ x, const float* __restrict__ Wq,
    const float* __restrict__ Wk, const float* __restrict__ Wv,
    const float* __restrict__ Wo, u16* __restrict__ Wb,
    float* __restrict__ stats, u16* __restrict__ xT) {
    const int id = blockIdx.x;
    const int tid = threadIdx.x;
    __shared__ u16 t[64][72];
    if (id < 1024) {
        // ---- tcast: x[n][c][l] f32 -> xT[n][l][c] bf16 ----
        const int n = id >> 8;
        const int c0 = ((id >> 6) & 3) * 64, l0 = (id & 63) * 64;
        const float* xs = x + (size_t)n * CH * LL;
        const int lq = (tid & 15) * 4, cc = tid >> 4;
#pragma unroll
        for (int p = 0; p < 4; ++p) {
            int c = cc + p * 16;
            float4 v = *(const float4*)&xs[(size_t)(c0 + c) * LL + l0 + lq];
            t[lq + 0][c] = f2b(v.x);
            t[lq + 1][c] = f2b(v.y);
            t[lq + 2][c] = f2b(v.z);
            t[lq + 3][c] = f2b(v.w);
        }
        __syncthreads();
        u16* xo = xT + (size_t)n * LL * CH;
        const int l = tid >> 2, c8 = (tid & 3) * 16;
#pragma unroll
        for (int h = 0; h < 2; ++h) {
            uint4 vv = *(uint4*)&t[l][c8 + h * 8];
            *(uint4*)&xo[(size_t)(l0 + l) * CH + c0 + c8 + h * 8] = vv;
        }
    } else {
        // ---- castw: weights f32 -> bf16 Wb[mat][d][c]; zero BN stats ----
        const int j = id - 1024;
        const int i = (j & 63) * 256 + tid;
        const int m = j >> 6;
        if (m == 0 && (j & 63) < 2) stats[i] = 0.0f;
        const float* src = (m == 0) ? Wq : (m == 1) ? Wk : (m == 2) ? Wv : Wo;
        float4 v = ((const float4*)src)[i];
        uint2 o;
        o.x = pack2(v.x, v.y);
        o.y = pack2(v.z, v.w);
        ((uint2*)(Wb + m * 65536))[i] = o;
    }
}

// ---------------------------------------------------------------------------
// Kernel 1: fused projqk + projv (R16, kept). LDS-staged B-operand.
// ids [0,1024): q/k projection; ids [1024,1536): v projection.
// ---------------------------------------------------------------------------
__global__ __launch_bounds__(256, 2) void proj_kernel(
    const u16* __restrict__ xT, const u16* __restrict__ Wb,
    u16* __restrict__ q, u16* __restrict__ k, u16* __restrict__ vT) {
    const int id = blockIdx.x;
    const int tid = threadIdx.x;
    const int w = tid >> 6, lane = tid & 63;
    const int lhi = lane >> 4, llo = lane & 15;

    __shared__ __align__(16) u16 Bs[128 * 256];  // 64 KB, chunk-XOR swizzled

    if (id < 1024) {
        // ---- projqk ----
        const int n = id >> 8;
        const int yy = (id >> 6) & 3;
        const int dhalf = yy & 1, mat = yy >> 1;
        const int l0 = (id & 63) * 64;
        const int d0 = dhalf * 128;

        const u16* xn = xT + (size_t)n * LL * CH;
        const u16* Wm = Wb + mat * 65536 + (size_t)d0 * CH;

#pragma unroll
        for (int i = 0; i < 16; ++i) {
            int s = i * 256 + tid;
            int r = s >> 5, c = s & 31;
            __builtin_amdgcn_global_load_lds(GPTR(Wm + r * CH + (c ^ (r & 31)) * 8),
                                             LPTR((char*)Bs + i * 4096 + w * 1024),
                                             16, 0, 0);
        }

        bf16x8 af[8];
        const u16* abase = xn + (size_t)(l0 + w * 16 + llo) * CH + lhi * 8;
#pragma unroll
        for (int ks = 0; ks < 8; ++ks) af[ks] = *(const bf16x8*)(abase + ks * 32);

        f32x4 acc[8];
#pragma unroll
        for (int t = 0; t < 8; ++t) acc[t] = (f32x4){0.f, 0.f, 0.f, 0.f};

        __syncthreads();

#pragma unroll
        for (int ks = 0; ks < 8; ++ks) {
#pragma unroll
            for (int ct = 0; ct < 8; ++ct) {
                const int rr = ct * 16 + llo;
                bf16x8 bf = *(const bf16x8*)(Bs + rr * CH +
                                             ((ks * 4 + lhi) ^ (rr & 31)) * 8);
                acc[ct] = __builtin_amdgcn_mfma_f32_16x16x32_bf16(af[ks], bf, acc[ct], 0, 0, 0);
            }
        }

        u16* o = (mat ? k : q) + (size_t)n * LL * CH;
#pragma unroll
        for (int r = 0; r < 4; ++r) {
            int lr = l0 + w * 16 + lhi * 4 + r;
#pragma unroll
            for (int ct = 0; ct < 8; ++ct)
                o[(size_t)lr * CH + d0 + ct * 16 + llo] = f2b(acc[ct][r]);
        }
    } else {
        // ---- projv ----
        const int j = id - 1024;
        const int n = j >> 7;
        const int d0 = ((j >> 5) & 3) * 64;
        const int l0 = (j & 31) * 128;

        const u16* xn = xT + (size_t)n * LL * CH + (size_t)l0 * CH;
        const u16* Wm = Wb + 2 * 65536;

#pragma unroll
        for (int i = 0; i < 16; ++i) {
            int s = i * 256 + tid;
            int r = s >> 5, c = s & 31;
            __builtin_amdgcn_global_load_lds(GPTR(xn + r * CH + (c ^ (r & 31)) * 8),
                                             LPTR((char*)Bs + i * 4096 + w * 1024),
                                             16, 0, 0);
        }

        bf16x8 af[8];
        const u16* abase = Wm + (size_t)(d0 + w * 16 + llo) * CH + lhi * 8;
#pragma unroll
        for (int ks = 0; ks < 8; ++ks) af[ks] = *(const bf16x8*)(abase + ks * 32);

        f32x4 acc[8];
#pragma unroll
        for (int t = 0; t < 8; ++t) acc[t] = (f32x4){0.f, 0.f, 0.f, 0.f};

        __syncthreads();

#pragma unroll
        for (int ks = 0; ks < 8; ++ks) {
#pragma unroll
            for (int ct = 0; ct < 8; ++ct) {
                const int rr = ct * 16 + llo;
                bf16x8 bf = *(const bf16x8*)(Bs + rr * CH +
                                             ((ks * 4 + lhi) ^ (rr & 31)) * 8);
                acc[ct] = __builtin_amdgcn_mfma_f32_16x16x32_bf16(af[ks], bf, acc[ct], 0, 0, 0);
            }
        }

        u16* o = vT + (size_t)n * CH * LL;
#pragma unroll
        for (int r = 0; r < 4; ++r) {
            int dr = d0 + w * 16 + lhi * 4 + r;
#pragma unroll
            for (int ct = 0; ct < 8; ++ct)
                o[(size_t)dr * LL + l0 + ct * 16 + llo] = f2b(acc[ct][r]);
        }
    }
}

// ---------------------------------------------------------------------------
// Kernel 2: bf16 flash attention (R19, FROZEN control: 72.5 us, MfmaUtil 44,
// bank conflicts 0). 32x32x16 MFMA; swapped QK^T; P->A-frag via
// cvt_pk_bf16 + permlane32_swap; double-buffered K/V via global_load_lds
// with chunk-XOR swizzles. LDS 65536, 2 blk/CU, setprio on MFMA clusters.
// ---------------------------------------------------------------------------
__global__ __launch_bounds__(256, 2) void fattn_kernel(
    const u16* __restrict__ q, const u16* __restrict__ k,
    const u16* __restrict__ vT, u16* __restrict__ Op, float* __restrict__ l_s,
    int iters) {
    const int n = blockIdx.y;
    const int s_id = blockIdx.z;
    const int l0 = blockIdx.x * 128;
    const int m_base = s_id * iters * 32;
    const int tid = threadIdx.x;
    const int w = tid >> 6;
    const int lane = tid & 63;
    const int l31 = lane & 31;
    const int h = lane >> 5;

    __shared__ __align__(16) char smem[65536];
    // K buffers @ 0 / 16384 ; V buffers @ 32768 / 49152

    // ---- Q fragments: lane holds Q[q=w*32+l31][c = s*16 + h*8 .. +8] ----
    bf16x8 qf[16];
    {
        const u16* base = q + (size_t)(n * LL + l0 + w * 32 + l31) * CH + h * 8;
#pragma unroll
        for (int s = 0; s < 16; ++s) qf[s] = *(const bf16x8*)(base + s * 16);
    }

    const u16* kg = k + (size_t)n * LL * CH;
    const u16* vg = vT + (size_t)n * CH * LL;

    // iter-invariant swizzled staging offsets (u16 elems); slot s = i*256+tid
    int okK[4], okV[4];
#pragma unroll
    for (int i = 0; i < 4; ++i) {
        int s = i * 256 + tid;
        int rK = s >> 5;
        int cK = (s & 31) ^ rK;
        okK[i] = rK * CH + cK * 8;
        int dV = s >> 2;
        int cV = (s & 3) ^ ((dV & 3) ^ ((dV >> 2) & 3));
        okV[i] = dV * LL + cV * 8;
    }

    f32x16 oacc[8];
#pragma unroll
    for (int t = 0; t < 8; ++t)
        oacc[t] = (f32x16){0.f, 0.f, 0.f, 0.f, 0.f, 0.f, 0.f, 0.f,
                           0.f, 0.f, 0.f, 0.f, 0.f, 0.f, 0.f, 0.f};
    float lrun = 0.f;

    const float C1 = 0.09016844005556021f;  // (1/16) * log2(e)
    const int kx = h ^ l31;                              // K read chunk XOR
    const int hg = h ^ ((lane & 3) ^ ((lane >> 2) & 3)); // V read chunk base

    // ---- prologue: issue tile 0 into buffer 0 ----
    {
        const u16* kg2 = kg + (size_t)m_base * CH;
        const u16* vg2 = vg + m_base;
#pragma unroll
        for (int i = 0; i < 4; ++i) {
            __builtin_amdgcn_global_load_lds(GPTR(kg2 + okK[i]),
                                             LPTR(smem + i * 4096 + w * 1024), 16, 0, 0);
            __builtin_amdgcn_global_load_lds(GPTR(vg2 + okV[i]),
                                             LPTR(smem + 32768 + i * 4096 + w * 1024),
                                             16, 0, 0);
        }
    }

    for (int it = 0; it < iters; ++it) {
        __syncthreads();
        if (it + 1 < iters) {
            const int m1 = m_base + (it + 1) * 32;
            const u16* kg2 = kg + (size_t)m1 * CH;
            const u16* vg2 = vg + m1;
            char* Kb = smem + ((it + 1) & 1) * 16384;
            char* Vb = smem + 32768 + ((it + 1) & 1) * 16384;
#pragma unroll
            for (int i = 0; i < 4; ++i) {
                __builtin_amdgcn_global_load_lds(GPTR(kg2 + okK[i]),
                                                 LPTR(Kb + i * 4096 + w * 1024), 16, 0, 0);
                __builtin_amdgcn_global_load_lds(GPTR(vg2 + okV[i]),
                                                 LPTR(Vb + i * 4096 + w * 1024), 16, 0, 0);
            }
        }
        const u16* Kl = (const u16*)(smem + (it & 1) * 16384);
        const u16* Vl = (const u16*)(smem + 32768 + (it & 1) * 16384);

        // ---- S^T = K*Q^T as one 32x32x16 chain over 16 c-steps ----
        f32x16 sacc = (f32x16){0.f, 0.f, 0.f, 0.f, 0.f, 0.f, 0.f, 0.f,
                               0.f, 0.f, 0.f, 0.f, 0.f, 0.f, 0.f, 0.f};
        __builtin_amdgcn_s_setprio(1);
#pragma unroll
        for (int s = 0; s < 16; ++s) {
            bf16x8 af = *(const bf16x8*)(Kl + l31 * 256 + ((2 * s) ^ kx) * 8);
            sacc = __builtin_amdgcn_mfma_f32_32x32x16_bf16(af, qf[s], sacc, 0, 0, 0);
        }
        __builtin_amdgcn_s_setprio(0);

        // ---- softmax: p = exp2(s*C1); pack pairs W[g][j]; lrun += sum ----
        u32 W[4][2];
#pragma unroll
        for (int g = 0; g < 4; ++g) {
            float p0 = __builtin_amdgcn_exp2f(sacc[4 * g + 0] * C1);
            float p1 = __builtin_amdgcn_exp2f(sacc[4 * g + 1] * C1);
            float p2 = __builtin_amdgcn_exp2f(sacc[4 * g + 2] * C1);
            float p3 = __builtin_amdgcn_exp2f(sacc[4 * g + 3] * C1);
            lrun += (p0 + p1) + (p2 + p3);
            asm("v_cvt_pk_bf16_f32 %0, %1, %2" : "=v"(W[g][0]) : "v"(p0), "v"(p1));
            asm("v_cvt_pk_bf16_f32 %0, %1, %2" : "=v"(W[g][1]) : "v"(p2), "v"(p3));
        }

        // ---- P->A-frags via permlane32_swap: word j = new vdst,
        // word 2+j = new vsrc of swap(vdst=W[2sp][j], vsrc=W[2sp+1][j]) ----
        bf16x8 pa[2];
#pragma unroll
        for (int sp = 0; sp < 2; ++sp) {
            u32 a0 = W[2 * sp][0], b0 = W[2 * sp + 1][0];
            asm("v_permlane32_swap_b32 %0, %1" : "+v"(a0), "+v"(b0));
            u32 a1 = W[2 * sp][1], b1 = W[2 * sp + 1][1];
            asm("v_permlane32_swap_b32 %0, %1" : "+v"(a1), "+v"(b1));
            union { u32 u[4]; bf16x8 v; } pk;
            pk.u[0] = a0;
            pk.u[1] = a1;
            pk.u[2] = b0;
            pk.u[3] = b1;
            pa[sp] = pk.v;
        }

        // ---- PV: O[q][d], 8 d-tiles x 2 k-steps of 32x32x16 ----
        __builtin_amdgcn_s_setprio(1);
#pragma unroll
        for (int sp = 0; sp < 2; ++sp) {
#pragma unroll
            for (int dt = 0; dt < 8; ++dt) {
                bf16x8 vf = *(const bf16x8*)(Vl + (dt * 32 + l31) * 32 +
                                             ((2 * sp) ^ hg) * 8);
                oacc[dt] = __builtin_amdgcn_mfma_f32_32x32x16_bf16(pa[sp], vf, oacc[dt], 0, 0, 0);
            }
        }
        __builtin_amdgcn_s_setprio(0);
    }

    // ---- epilogue: store un-normalized partial O (bf16) + l (fp32) ----
    u16* ap = Op + (size_t)((s_id * NB + n) * (size_t)LL + l0 + w * 32) * CH;
    float* lp = l_s + (size_t)s_id * NB * LL + (size_t)n * LL + l0 + w * 32;
    lrun += __shfl_xor(lrun, 32);
    if (h == 0) lp[l31] = lrun;
#pragma unroll
    for (int dt = 0; dt < 8; ++dt) {
#pragma unroll
        for (int r = 0; r < 16; ++r) {
            int qrow = (r & 3) + 8 * (r >> 2) + 4 * h;
            ap[(size_t)qrow * CH + dt * 32 + l31] = f2b(oacc[dt][r]);
        }
    }
}

// ---------------------------------------------------------------------------
// Kernel 3: FUSED merge + output projection + BN partials (R20).
// R9 audit: merge wrote att (8.4 MB) and outm's 4-blocks-per-l-tile grid
// re-read it 4x (33.5 MB) -> 75 MB of traffic to move an 8.4 MB payload.
// R20: one block per 32-row l-tile covers ALL 256 outputs (grid 128 x 4 =
// 512 blocks, 2/CU). Staging computes att on the fly: att = (sum_s Op[s]) *
// (1/sum_s l_s[s]) -- same adds in the same order as merge (bit-identical),
// packed bf16, written to LINEAR LDS slots with the chunk-XOR source
// permutation (c^r) the old global_load_lds staging used; the MFMA read side
// keeps outm's proven (cq^rr) formula (rr<32 so rr&31 == rr). Weights: af
// registers reloaded per o0 (L2-hot). Op read ONCE (33.5 MB total); att
// never materialized; one launch removed.
// ---------------------------------------------------------------------------
__global__ __launch_bounds__(256, 2) void outm_kernel(
    const u16* __restrict__ Wb, const u16* __restrict__ Op,
    const float* __restrict__ l_s, u16* __restrict__ y,
    float* __restrict__ stats, int S) {
    const int n = blockIdx.y;
    const int l0 = blockIdx.x * 32;
    const int tid = threadIdx.x;
    const int w = tid >> 6, lane = tid & 63;
    const int lhi = lane >> 4, llo = lane & 15;

    __shared__ __align__(16) u16 Bs[32 * 256];  // 16 KB att tile, chunk-XOR

    const u16* Wm = Wb + 3 * 65536;
    const size_t opbase = (size_t)n * LL * CH + (size_t)l0 * CH;
    const size_t sstride = (size_t)NB * LL * CH;

    // ---- stage: slot s = i*256+tid; r = s>>5 (row 0..31), c = s&31 (chunk).
    // Source chunk pre-swizzled c^r; dest linear slot*16B. ----
#pragma unroll
    for (int i = 0; i < 4; ++i) {
        int s = i * 256 + tid;
        int r = s >> 5, c = s & 31;
        const u16* src = Op + opbase + (size_t)r * CH + (c ^ r) * 8;
        float lsum = 0.0f;
        for (int sp = 0; sp < S; ++sp)
            lsum += l_s[(size_t)sp * NB * LL + (size_t)n * LL + l0 + r];
        const float inv = 1.0f / lsum;
        float acc[8];
#pragma unroll
        for (int j = 0; j < 8; ++j) acc[j] = 0.0f;
        for (int sp = 0; sp < S; ++sp) {
            uint4 raw = *(const uint4*)(src + (size_t)sp * sstride);
            acc[0] += blo(raw.x); acc[1] += bhi(raw.x);
            acc[2] += blo(raw.y); acc[3] += bhi(raw.y);
            acc[4] += blo(raw.z); acc[5] += bhi(raw.z);
            acc[6] += blo(raw.w); acc[7] += bhi(raw.w);
        }
        uint4 o;
        o.x = pack2(acc[0] * inv, acc[1] * inv);
        o.y = pack2(acc[2] * inv, acc[3] * inv);
        o.z = pack2(acc[4] * inv, acc[5] * inv);
        o.w = pack2(acc[6] * inv, acc[7] * inv);
        *(uint4*)(Bs + (size_t)s * 8) = o;
    }

    __syncthreads();

    u16* yn = y + (size_t)n * CH * LL;
#pragma unroll
    for (int o0 = 0; o0 < 4; ++o0) {
        bf16x8 af[8];
        const u16* abase = Wm + (size_t)(o0 * 64 + w * 16 + llo) * CH + lhi * 8;
#pragma unroll
        for (int ks = 0; ks < 8; ++ks) af[ks] = *(const bf16x8*)(abase + ks * 32);

        f32x4 acc[2];
        acc[0] = (f32x4){0.f, 0.f, 0.f, 0.f};
        acc[1] = (f32x4){0.f, 0.f, 0.f, 0.f};
#pragma unroll
        for (int ks = 0; ks < 8; ++ks) {
#pragma unroll
            for (int ct = 0; ct < 2; ++ct) {
                const int rr = ct * 16 + llo;  // 0..31
                bf16x8 bf = *(const bf16x8*)(Bs + rr * CH +
                                             ((ks * 4 + lhi) ^ rr) * 8);
                acc[ct] = __builtin_amdgcn_mfma_f32_16x16x32_bf16(af[ks], bf, acc[ct], 0, 0, 0);
            }
        }

#pragma unroll
        for (int r = 0; r < 4; ++r) {
            const int orow = o0 * 64 + w * 16 + lhi * 4 + r;
            float ts = 0.0f, tq = 0.0f;
#pragma unroll
            for (int ct = 0; ct < 2; ++ct) {
                float vv = acc[ct][r];
                yn[(size_t)orow * LL + l0 + ct * 16 + llo] = f2b(vv);
                ts += vv;
                tq += vv * vv;
            }
            ts += __shfl_xor(ts, 1); tq += __shfl_xor(tq, 1);
            ts += __shfl_xor(ts, 2); tq += __shfl_xor(tq, 2);
            ts += __shfl_xor(ts, 4); tq += __shfl_xor(tq, 4);
            ts += __shfl_xor(ts, 8); tq += __shfl_xor(tq, 8);
            if (llo == 0) {
                atomicAdd(&stats[orow], ts);
                atomicAdd(&stats[256 + orow], tq);
            }
        }
    }
}

// ---------------------------------------------------------------------------
// Kernel 4: BN apply (batch stats, biased var) + residual. y read as bf16.
// ---------------------------------------------------------------------------
__global__ __launch_bounds__(256) void bn_kernel(
    const float* __restrict__ x, const u16* __restrict__ y,
    const float* __restrict__ stats, const float* __restrict__ gamma,
    const float* __restrict__ beta, float* __restrict__ out) {
    const int idx = blockIdx.x * 256 + threadIdx.x;  // per 4 elems
    const int base = idx * 4;
    const int c = (base >> 12) & 255;  // (base / L) % C
    const float cnt = 1.0f / 16384.0f; // N*L
    float mean = stats[c] * cnt;
    float var = stats[256 + c] * cnt - mean * mean;
    float rstd = rsqrtf(var + 1e-4f);
    float g = gamma[c] * rstd;
    float b = beta[c];
    uint2 yv = ((const uint2*)y)[idx];
    float4 xv = ((const float4*)x)[idx];
    float4 o;
    o.x = xv.x + (blo(yv.x) - mean) * g + b;
    o.y = xv.y + (bhi(yv.x) - mean) * g + b;
    o.z = xv.z + (blo(yv.y) - mean) * g + b;
    o.w = xv.w + (bhi(yv.y) - mean) * g + b;
    ((float4*)out)[idx] = o;
}

// ---------------------------------------------------------------------------
extern "C" void kernel_launch(void* const* d_in, const int* in_sizes, int n_in,
                              void* d_out, int out_size, void* d_ws, size_t ws_size,
                              hipStream_t stream) {
    const float* x = (const float*)d_in[0];
    const float* Wq = (const float*)d_in[1];
    const float* Wk = (const float*)d_in[2];
    const float* Wv = (const float*)d_in[3];
    const float* Wo = (const float*)d_in[4];
    const float* gamma = (const float*)d_in[5];
    const float* beta = (const float*)d_in[6];
    float* out = (float*)d_out;

    const size_t elems = (size_t)NB * LL * CH;  // 4,194,304

    // pick largest split count whose workspace fits (S=4 needs ~59.4 MB)
    int S = 1;
    for (int cand = 4; cand >= 2; cand >>= 1) {
        size_t need = elems * 2 * (size_t)(3 + cand) +
                      (size_t)cand * NB * LL * 4 + 524288 + 8192;
        if (ws_size >= need) { S = cand; break; }
    }
    const int iters = 128 / S;

    char* wsb = (char*)d_ws;
    u16* q = (u16*)wsb;                             // 8.39 MB (bf16)
    u16* k = q + elems;                             // 8.39 MB (bf16)
    u16* vT = k + elems;                            // 8.39 MB (bf16)
    u16* Op = vT + elems;                           // S * 8.39 MB (bf16)
    u16* xT = Op;                                   // overlay: dead before fattn
    float* l_s = (float*)(Op + (size_t)S * elems);  // S * 64 KB
    u16* Wb = (u16*)(l_s + (size_t)S * NB * LL);    // 512 KB
    float* stats = (float*)(Wb + 4 * 65536);        // 2 KB
    u16* y = k;     // overlay k (dead after fattn)

    prep_kernel<<<1280, 256, 0, stream>>>(x, Wq, Wk, Wv, Wo, Wb, stats, xT);
    proj_kernel<<<1536, 256, 0, stream>>>(xT, Wb, q, k, vT);
    fattn_kernel<<<dim3(LL / 128, NB, S), 256, 0, stream>>>(q, k, vT, Op, l_s, iters);
    outm_kernel<<<dim3(LL / 32, NB), 256, 0, stream>>>(Wb, Op, l_s, y, stats, S);
    bn_kernel<<<(NB * CH * LL / 4) / 256, 256, 0, stream>>>(x, y, stats, gamma, beta, out);
}

// Round 11
// 194.988 us; speedup vs baseline: 1.4030x; 1.4030x over previous
//
#include <hip/hip_runtime.h>
#include <cstdint>
#include <cstddef>

// Problem constants: N=4, C=D=256, H=W=64, L=4096
#define NB 4
#define CH 256
#define LL 4096

typedef unsigned short u16;
typedef unsigned int u32;
typedef unsigned char u8;
typedef __attribute__((ext_vector_type(8))) short bf16x8;
typedef __attribute__((ext_vector_type(4))) float f32x4;
typedef __attribute__((ext_vector_type(16))) float f32x16;

#define GPTR(p) ((const __attribute__((address_space(1))) u32*)(p))
#define LPTR(p) ((__attribute__((address_space(3))) u32*)(p))

__device__ __forceinline__ float blo(u32 x) { return __uint_as_float(x << 16); }
__device__ __forceinline__ float bhi(u32 x) { return __uint_as_float(x & 0xffff0000u); }
__device__ __forceinline__ float b2f(u16 h) { return __uint_as_float(((u32)h) << 16); }
__device__ __forceinline__ u16 f2b(float f) {
    u32 u = __float_as_uint(f);
    u32 r = (u + 0x7fffu + ((u >> 16) & 1u)) >> 16;  // RNE
    return (u16)r;
}
__device__ __forceinline__ u32 pack2(float a, float b) {
    return (u32)f2b(a) | ((u32)f2b(b) << 16);
}

// ---------------------------------------------------------------------------
// Kernel P: fused castw + tcast (R16, kept).
// ids [0,1024): tcast 64x64 tile; ids [1024,1280): castw + stats zero.
// ---------------------------------------------------------------------------
__global__ __launch_bounds__(256) void prep_kernel(
    const float* __restrict__ x, const float* __restrict__ Wq,
    const float* __restrict__ Wk, const float* __restrict__ Wv,
    const float* __restrict__ Wo, u16* __restrict__ Wb,
    float* __restrict__ stats, u16* __restrict__ xT) {
    const int id = blockIdx.x;
    const int tid = threadIdx.x;
    __shared__ u16 t[64][72];
    if (id < 1024) {
        // ---- tcast: x[n][c][l] f32 -> xT[n][l][c] bf16 ----
        const int n = id >> 8;
        const int c0 = ((id >> 6) & 3) * 64, l0 = (id & 63) * 64;
        const float* xs = x + (size_t)n * CH * LL;
        const int lq = (tid & 15) * 4, cc = tid >> 4;
#pragma unroll
        for (int p = 0; p < 4; ++p) {
            int c = cc + p * 16;
            float4 v = *(const float4*)&xs[(size_t)(c0 + c) * LL + l0 + lq];
            t[lq + 0][c] = f2b(v.x);
            t[lq + 1][c] = f2b(v.y);
            t[lq + 2][c] = f2b(v.z);
            t[lq + 3][c] = f2b(v.w);
        }
        __syncthreads();
        u16* xo = xT + (size_t)n * LL * CH;
        const int l = tid >> 2, c8 = (tid & 3) * 16;
#pragma unroll
        for (int h = 0; h < 2; ++h) {
            uint4 vv = *(uint4*)&t[l][c8 + h * 8];
            *(uint4*)&xo[(size_t)(l0 + l) * CH + c0 + c8 + h * 8] = vv;
        }
    } else {
        // ---- castw: weights f32 -> bf16 Wb[mat][d][c]; zero BN stats ----
        const int j = id - 1024;
        const int i = (j & 63) * 256 + tid;
        const int m = j >> 6;
        if (m == 0 && (j & 63) < 2) stats[i] = 0.0f;
        const float* src = (m == 0) ? Wq : (m == 1) ? Wk : (m == 2) ? Wv : Wo;
        float4 v = ((const float4*)src)[i];
        uint2 o;
        o.x = pack2(v.x, v.y);
        o.y = pack2(v.z, v.w);
        ((uint2*)(Wb + m * 65536))[i] = o;
    }
}

// ---------------------------------------------------------------------------
// Kernel 1: fused projqk + projv (R16, kept). LDS-staged B-operand.
// ids [0,1024): q/k projection; ids [1024,1536): v projection.
// ---------------------------------------------------------------------------
__global__ __launch_bounds__(256, 2) void proj_kernel(
    const u16* __restrict__ xT, const u16* __restrict__ Wb,
    u16* __restrict__ q, u16* __restrict__ k, u16* __restrict__ vT) {
    const int id = blockIdx.x;
    const int tid = threadIdx.x;
    const int w = tid >> 6, lane = tid & 63;
    const int lhi = lane >> 4, llo = lane & 15;

    __shared__ __align__(16) u16 Bs[128 * 256];  // 64 KB, chunk-XOR swizzled

    if (id < 1024) {
        // ---- projqk ----
        const int n = id >> 8;
        const int yy = (id >> 6) & 3;
        const int dhalf = yy & 1, mat = yy >> 1;
        const int l0 = (id & 63) * 64;
        const int d0 = dhalf * 128;

        const u16* xn = xT + (size_t)n * LL * CH;
        const u16* Wm = Wb + mat * 65536 + (size_t)d0 * CH;

#pragma unroll
        for (int i = 0; i < 16; ++i) {
            int s = i * 256 + tid;
            int r = s >> 5, c = s & 31;
            __builtin_amdgcn_global_load_lds(GPTR(Wm + r * CH + (c ^ (r & 31)) * 8),
                                             LPTR((char*)Bs + i * 4096 + w * 1024),
                                             16, 0, 0);
        }

        bf16x8 af[8];
        const u16* abase = xn + (size_t)(l0 + w * 16 + llo) * CH + lhi * 8;
#pragma unroll
        for (int ks = 0; ks < 8; ++ks) af[ks] = *(const bf16x8*)(abase + ks * 32);

        f32x4 acc[8];
#pragma unroll
        for (int t = 0; t < 8; ++t) acc[t] = (f32x4){0.f, 0.f, 0.f, 0.f};

        __syncthreads();

#pragma unroll
        for (int ks = 0; ks < 8; ++ks) {
#pragma unroll
            for (int ct = 0; ct < 8; ++ct) {
                const int rr = ct * 16 + llo;
                bf16x8 bf = *(const bf16x8*)(Bs + rr * CH +
                                             ((ks * 4 + lhi) ^ (rr & 31)) * 8);
                acc[ct] = __builtin_amdgcn_mfma_f32_16x16x32_bf16(af[ks], bf, acc[ct], 0, 0, 0);
            }
        }

        u16* o = (mat ? k : q) + (size_t)n * LL * CH;
#pragma unroll
        for (int r = 0; r < 4; ++r) {
            int lr = l0 + w * 16 + lhi * 4 + r;
#pragma unroll
            for (int ct = 0; ct < 8; ++ct)
                o[(size_t)lr * CH + d0 + ct * 16 + llo] = f2b(acc[ct][r]);
        }
    } else {
        // ---- projv ----
        const int j = id - 1024;
        const int n = j >> 7;
        const int d0 = ((j >> 5) & 3) * 64;
        const int l0 = (j & 31) * 128;

        const u16* xn = xT + (size_t)n * LL * CH + (size_t)l0 * CH;
        const u16* Wm = Wb + 2 * 65536;

#pragma unroll
        for (int i = 0; i < 16; ++i) {
            int s = i * 256 + tid;
            int r = s >> 5, c = s & 31;
            __builtin_amdgcn_global_load_lds(GPTR(xn + r * CH + (c ^ (r & 31)) * 8),
                                             LPTR((char*)Bs + i * 4096 + w * 1024),
                                             16, 0, 0);
        }

        bf16x8 af[8];
        const u16* abase = Wm + (size_t)(d0 + w * 16 + llo) * CH + lhi * 8;
#pragma unroll
        for (int ks = 0; ks < 8; ++ks) af[ks] = *(const bf16x8*)(abase + ks * 32);

        f32x4 acc[8];
#pragma unroll
        for (int t = 0; t < 8; ++t) acc[t] = (f32x4){0.f, 0.f, 0.f, 0.f};

        __syncthreads();

#pragma unroll
        for (int ks = 0; ks < 8; ++ks) {
#pragma unroll
            for (int ct = 0; ct < 8; ++ct) {
                const int rr = ct * 16 + llo;
                bf16x8 bf = *(const bf16x8*)(Bs + rr * CH +
                                             ((ks * 4 + lhi) ^ (rr & 31)) * 8);
                acc[ct] = __builtin_amdgcn_mfma_f32_16x16x32_bf16(af[ks], bf, acc[ct], 0, 0, 0);
            }
        }

        u16* o = vT + (size_t)n * CH * LL;
#pragma unroll
        for (int r = 0; r < 4; ++r) {
            int dr = d0 + w * 16 + lhi * 4 + r;
#pragma unroll
            for (int ct = 0; ct < 8; ++ct)
                o[(size_t)dr * LL + l0 + ct * 16 + llo] = f2b(acc[ct][r]);
        }
    }
}

// ---------------------------------------------------------------------------
// Kernel 2: bf16 flash attention (R19, FROZEN control: 72.5 us, MfmaUtil 44,
// bank conflicts 0). 32x32x16 MFMA; swapped QK^T; P->A-frag via
// cvt_pk_bf16 + permlane32_swap; double-buffered K/V via global_load_lds
// with chunk-XOR swizzles. LDS 65536, 2 blk/CU, setprio on MFMA clusters.
// ---------------------------------------------------------------------------
__global__ __launch_bounds__(256, 2) void fattn_kernel(
    const u16* __restrict__ q, const u16* __restrict__ k,
    const u16* __restrict__ vT, u16* __restrict__ Op, float* __restrict__ l_s,
    int iters) {
    const int n = blockIdx.y;
    const int s_id = blockIdx.z;
    const int l0 = blockIdx.x * 128;
    const int m_base = s_id * iters * 32;
    const int tid = threadIdx.x;
    const int w = tid >> 6;
    const int lane = tid & 63;
    const int l31 = lane & 31;
    const int h = lane >> 5;

    __shared__ __align__(16) char smem[65536];
    // K buffers @ 0 / 16384 ; V buffers @ 32768 / 49152

    // ---- Q fragments: lane holds Q[q=w*32+l31][c = s*16 + h*8 .. +8] ----
    bf16x8 qf[16];
    {
        const u16* base = q + (size_t)(n * LL + l0 + w * 32 + l31) * CH + h * 8;
#pragma unroll
        for (int s = 0; s < 16; ++s) qf[s] = *(const bf16x8*)(base + s * 16);
    }

    const u16* kg = k + (size_t)n * LL * CH;
    const u16* vg = vT + (size_t)n * CH * LL;

    // iter-invariant swizzled staging offsets (u16 elems); slot s = i*256+tid
    int okK[4], okV[4];
#pragma unroll
    for (int i = 0; i < 4; ++i) {
        int s = i * 256 + tid;
        int rK = s >> 5;
        int cK = (s & 31) ^ rK;
        okK[i] = rK * CH + cK * 8;
        int dV = s >> 2;
        int cV = (s & 3) ^ ((dV & 3) ^ ((dV >> 2) & 3));
        okV[i] = dV * LL + cV * 8;
    }

    f32x16 oacc[8];
#pragma unroll
    for (int t = 0; t < 8; ++t)
        oacc[t] = (f32x16){0.f, 0.f, 0.f, 0.f, 0.f, 0.f, 0.f, 0.f,
                           0.f, 0.f, 0.f, 0.f, 0.f, 0.f, 0.f, 0.f};
    float lrun = 0.f;

    const float C1 = 0.09016844005556021f;  // (1/16) * log2(e)
    const int kx = h ^ l31;                              // K read chunk XOR
    const int hg = h ^ ((lane & 3) ^ ((lane >> 2) & 3)); // V read chunk base

    // ---- prologue: issue tile 0 into buffer 0 ----
    {
        const u16* kg2 = kg + (size_t)m_base * CH;
        const u16* vg2 = vg + m_base;
#pragma unroll
        for (int i = 0; i < 4; ++i) {
            __builtin_amdgcn_global_load_lds(GPTR(kg2 + okK[i]),
                                             LPTR(smem + i * 4096 + w * 1024), 16, 0, 0);
            __builtin_amdgcn_global_load_lds(GPTR(vg2 + okV[i]),
                                             LPTR(smem + 32768 + i * 4096 + w * 1024),
                                             16, 0, 0);
        }
    }

    for (int it = 0; it < iters; ++it) {
        __syncthreads();
        if (it + 1 < iters) {
            const int m1 = m_base + (it + 1) * 32;
            const u16* kg2 = kg + (size_t)m1 * CH;
            const u16* vg2 = vg + m1;
            char* Kb = smem + ((it + 1) & 1) * 16384;
            char* Vb = smem + 32768 + ((it + 1) & 1) * 16384;
#pragma unroll
            for (int i = 0; i < 4; ++i) {
                __builtin_amdgcn_global_load_lds(GPTR(kg2 + okK[i]),
                                                 LPTR(Kb + i * 4096 + w * 1024), 16, 0, 0);
                __builtin_amdgcn_global_load_lds(GPTR(vg2 + okV[i]),
                                                 LPTR(Vb + i * 4096 + w * 1024), 16, 0, 0);
            }
        }
        const u16* Kl = (const u16*)(smem + (it & 1) * 16384);
        const u16* Vl = (const u16*)(smem + 32768 + (it & 1) * 16384);

        // ---- S^T = K*Q^T as one 32x32x16 chain over 16 c-steps ----
        f32x16 sacc = (f32x16){0.f, 0.f, 0.f, 0.f, 0.f, 0.f, 0.f, 0.f,
                               0.f, 0.f, 0.f, 0.f, 0.f, 0.f, 0.f, 0.f};
        __builtin_amdgcn_s_setprio(1);
#pragma unroll
        for (int s = 0; s < 16; ++s) {
            bf16x8 af = *(const bf16x8*)(Kl + l31 * 256 + ((2 * s) ^ kx) * 8);
            sacc = __builtin_amdgcn_mfma_f32_32x32x16_bf16(af, qf[s], sacc, 0, 0, 0);
        }
        __builtin_amdgcn_s_setprio(0);

        // ---- softmax: p = exp2(s*C1); pack pairs W[g][j]; lrun += sum ----
        u32 W[4][2];
#pragma unroll
        for (int g = 0; g < 4; ++g) {
            float p0 = __builtin_amdgcn_exp2f(sacc[4 * g + 0] * C1);
            float p1 = __builtin_amdgcn_exp2f(sacc[4 * g + 1] * C1);
            float p2 = __builtin_amdgcn_exp2f(sacc[4 * g + 2] * C1);
            float p3 = __builtin_amdgcn_exp2f(sacc[4 * g + 3] * C1);
            lrun += (p0 + p1) + (p2 + p3);
            asm("v_cvt_pk_bf16_f32 %0, %1, %2" : "=v"(W[g][0]) : "v"(p0), "v"(p1));
            asm("v_cvt_pk_bf16_f32 %0, %1, %2" : "=v"(W[g][1]) : "v"(p2), "v"(p3));
        }

        // ---- P->A-frags via permlane32_swap: word j = new vdst,
        // word 2+j = new vsrc of swap(vdst=W[2sp][j], vsrc=W[2sp+1][j]) ----
        bf16x8 pa[2];
#pragma unroll
        for (int sp = 0; sp < 2; ++sp) {
            u32 a0 = W[2 * sp][0], b0 = W[2 * sp + 1][0];
            asm("v_permlane32_swap_b32 %0, %1" : "+v"(a0), "+v"(b0));
            u32 a1 = W[2 * sp][1], b1 = W[2 * sp + 1][1];
            asm("v_permlane32_swap_b32 %0, %1" : "+v"(a1), "+v"(b1));
            union { u32 u[4]; bf16x8 v; } pk;
            pk.u[0] = a0;
            pk.u[1] = a1;
            pk.u[2] = b0;
            pk.u[3] = b1;
            pa[sp] = pk.v;
        }

        // ---- PV: O[q][d], 8 d-tiles x 2 k-steps of 32x32x16 ----
        __builtin_amdgcn_s_setprio(1);
#pragma unroll
        for (int sp = 0; sp < 2; ++sp) {
#pragma unroll
            for (int dt = 0; dt < 8; ++dt) {
                bf16x8 vf = *(const bf16x8*)(Vl + (dt * 32 + l31) * 32 +
                                             ((2 * sp) ^ hg) * 8);
                oacc[dt] = __builtin_amdgcn_mfma_f32_32x32x16_bf16(pa[sp], vf, oacc[dt], 0, 0, 0);
            }
        }
        __builtin_amdgcn_s_setprio(0);
    }

    // ---- epilogue: store un-normalized partial O (bf16) + l (fp32) ----
    u16* ap = Op + (size_t)((s_id * NB + n) * (size_t)LL + l0 + w * 32) * CH;
    float* lp = l_s + (size_t)s_id * NB * LL + (size_t)n * LL + l0 + w * 32;
    lrun += __shfl_xor(lrun, 32);
    if (h == 0) lp[l31] = lrun;
#pragma unroll
    for (int dt = 0; dt < 8; ++dt) {
#pragma unroll
        for (int r = 0; r < 16; ++r) {
            int qrow = (r & 3) + 8 * (r >> 2) + 4 * h;
            ap[(size_t)qrow * CH + dt * 32 + l31] = f2b(oacc[dt][r]);
        }
    }
}

// ---------------------------------------------------------------------------
// Kernel 2c: merge splits (R9 REVERT -- R10's fusion into outm was 119 us at
// 0.7% MfmaUtil: traffic was L3-absorbed all along (FETCH 17 MB), and the
// fusion cut blocks 4096->512 with serial S-loop latency chains. The
// separate streaming pair costs ~15 us; parallelism > traffic here.)
// att[i] = (sum_s Op[s][i]) / (sum_s l_s[s][row])
// ---------------------------------------------------------------------------
__global__ __launch_bounds__(256) void merge_kernel(
    const u16* __restrict__ Op, const float* __restrict__ l_s,
    u16* __restrict__ att, int S) {
    const size_t t8 = (size_t)blockIdx.x * 256 + threadIdx.x;
    const size_t flat = t8 * 8;
    const size_t row = flat >> 8;
    float lsum = 0.0f;
    for (int s = 0; s < S; ++s) lsum += l_s[(size_t)s * NB * LL + row];
    const float inv = 1.0f / lsum;
    float acc[8];
#pragma unroll
    for (int j = 0; j < 8; ++j) acc[j] = 0.0f;
    for (int s = 0; s < S; ++s) {
        uint4 raw = *(const uint4*)(Op + (size_t)s * NB * LL * CH + flat);
        acc[0] += blo(raw.x); acc[1] += bhi(raw.x);
        acc[2] += blo(raw.y); acc[3] += bhi(raw.y);
        acc[4] += blo(raw.z); acc[5] += bhi(raw.z);
        acc[6] += blo(raw.w); acc[7] += bhi(raw.w);
    }
    uint4 o;
    o.x = pack2(acc[0] * inv, acc[1] * inv);
    o.y = pack2(acc[2] * inv, acc[3] * inv);
    o.z = pack2(acc[4] * inv, acc[5] * inv);
    o.w = pack2(acc[6] * inv, acc[7] * inv);
    *(uint4*)(att + flat) = o;
}

// ---------------------------------------------------------------------------
// Kernel 3: output projection via MFMA + fused BN partial sums. y bf16.
// B = att l-tile staged in LDS (R14 template; R9 form).
// ---------------------------------------------------------------------------
__global__ __launch_bounds__(256, 2) void outm_kernel(
    const u16* __restrict__ Wb, const u16* __restrict__ att,
    u16* __restrict__ y, float* __restrict__ stats) {
    const int n = blockIdx.z;
    const int o0 = blockIdx.y * 64;
    const int l0 = blockIdx.x * 128;
    const int tid = threadIdx.x;
    const int w = tid >> 6, lane = tid & 63;
    const int lhi = lane >> 4, llo = lane & 15;

    __shared__ __align__(16) u16 Bs[128 * 256];  // 64 KB

    const u16* an = att + (size_t)n * LL * CH + (size_t)l0 * CH;
    const u16* Wm = Wb + 3 * 65536;

#pragma unroll
    for (int i = 0; i < 16; ++i) {
        int s = i * 256 + tid;
        int r = s >> 5, c = s & 31;
        __builtin_amdgcn_global_load_lds(GPTR(an + r * CH + (c ^ (r & 31)) * 8),
                                         LPTR((char*)Bs + i * 4096 + w * 1024),
                                         16, 0, 0);
    }

    bf16x8 af[8];
    const u16* abase = Wm + (size_t)(o0 + w * 16 + llo) * CH + lhi * 8;
#pragma unroll
    for (int ks = 0; ks < 8; ++ks) af[ks] = *(const bf16x8*)(abase + ks * 32);

    f32x4 acc[8];
#pragma unroll
    for (int t = 0; t < 8; ++t) acc[t] = (f32x4){0.f, 0.f, 0.f, 0.f};

    __syncthreads();

#pragma unroll
    for (int ks = 0; ks < 8; ++ks) {
#pragma unroll
        for (int ct = 0; ct < 8; ++ct) {
            const int rr = ct * 16 + llo;
            bf16x8 bf = *(const bf16x8*)(Bs + rr * CH +
                                         ((ks * 4 + lhi) ^ (rr & 31)) * 8);
            acc[ct] = __builtin_amdgcn_mfma_f32_16x16x32_bf16(af[ks], bf, acc[ct], 0, 0, 0);
        }
    }

    u16* yn = y + (size_t)n * CH * LL;
#pragma unroll
    for (int r = 0; r < 4; ++r) {
        const int orow = o0 + w * 16 + lhi * 4 + r;
        float ts = 0.0f, tq = 0.0f;
#pragma unroll
        for (int ct = 0; ct < 8; ++ct) {
            float vv = acc[ct][r];
            yn[(size_t)orow * LL + l0 + ct * 16 + llo] = f2b(vv);
            ts += vv;
            tq += vv * vv;
        }
        ts += __shfl_xor(ts, 1); tq += __shfl_xor(tq, 1);
        ts += __shfl_xor(ts, 2); tq += __shfl_xor(tq, 2);
        ts += __shfl_xor(ts, 4); tq += __shfl_xor(tq, 4);
        ts += __shfl_xor(ts, 8); tq += __shfl_xor(tq, 8);
        if (llo == 0) {
            atomicAdd(&stats[orow], ts);
            atomicAdd(&stats[256 + orow], tq);
        }
    }
}

// ---------------------------------------------------------------------------
// Kernel 4: BN apply (batch stats, biased var) + residual. y read as bf16.
// R21: widened 4->8 elems/thread (uint4 y + 2x float4 x, 32B/lane); same
// per-element math; c constant across the 8-group (8 | 4096).
// ---------------------------------------------------------------------------
__global__ __launch_bounds__(256) void bn_kernel(
    const float* __restrict__ x, const u16* __restrict__ y,
    const float* __restrict__ stats, const float* __restrict__ gamma,
    const float* __restrict__ beta, float* __restrict__ out) {
    const int idx = blockIdx.x * 256 + threadIdx.x;  // per 8 elems
    const int base = idx * 8;
    const int c = (base >> 12) & 255;  // (base / L) % C
    const float cnt = 1.0f / 16384.0f; // N*L
    float mean = stats[c] * cnt;
    float var = stats[256 + c] * cnt - mean * mean;
    float rstd = rsqrtf(var + 1e-4f);
    float g = gamma[c] * rstd;
    float b = beta[c];
    uint4 yv = ((const uint4*)y)[idx];
    float4 xv0 = ((const float4*)x)[idx * 2];
    float4 xv1 = ((const float4*)x)[idx * 2 + 1];
    float4 o0, o1;
    o0.x = xv0.x + (blo(yv.x) - mean) * g + b;
    o0.y = xv0.y + (bhi(yv.x) - mean) * g + b;
    o0.z = xv0.z + (blo(yv.y) - mean) * g + b;
    o0.w = xv0.w + (bhi(yv.y) - mean) * g + b;
    o1.x = xv1.x + (blo(yv.z) - mean) * g + b;
    o1.y = xv1.y + (bhi(yv.z) - mean) * g + b;
    o1.z = xv1.z + (blo(yv.w) - mean) * g + b;
    o1.w = xv1.w + (bhi(yv.w) - mean) * g + b;
    ((float4*)out)[idx * 2] = o0;
    ((float4*)out)[idx * 2 + 1] = o1;
}

// ---------------------------------------------------------------------------
extern "C" void kernel_launch(void* const* d_in, const int* in_sizes, int n_in,
                              void* d_out, int out_size, void* d_ws, size_t ws_size,
                              hipStream_t stream) {
    const float* x = (const float*)d_in[0];
    const float* Wq = (const float*)d_in[1];
    const float* Wk = (const float*)d_in[2];
    const float* Wv = (const float*)d_in[3];
    const float* Wo = (const float*)d_in[4];
    const float* gamma = (const float*)d_in[5];
    const float* beta = (const float*)d_in[6];
    float* out = (float*)d_out;

    const size_t elems = (size_t)NB * LL * CH;  // 4,194,304

    // pick largest split count whose workspace fits (S=4 needs ~59.4 MB)
    int S = 1;
    for (int cand = 4; cand >= 2; cand >>= 1) {
        size_t need = elems * 2 * (size_t)(3 + cand) +
                      (size_t)cand * NB * LL * 4 + 524288 + 8192;
        if (ws_size >= need) { S = cand; break; }
    }
    const int iters = 128 / S;

    char* wsb = (char*)d_ws;
    u16* q = (u16*)wsb;                             // 8.39 MB (bf16)
    u16* k = q + elems;                             // 8.39 MB (bf16)
    u16* vT = k + elems;                            // 8.39 MB (bf16)
    u16* Op = vT + elems;                           // S * 8.39 MB (bf16)
    u16* xT = Op;                                   // overlay: dead before fattn
    float* l_s = (float*)(Op + (size_t)S * elems);  // S * 64 KB
    u16* Wb = (u16*)(l_s + (size_t)S * NB * LL);    // 512 KB
    float* stats = (float*)(Wb + 4 * 65536);        // 2 KB
    u16* att = q;   // overlay q (dead after fattn)
    u16* y = k;     // overlay k (dead after merge)

    prep_kernel<<<1280, 256, 0, stream>>>(x, Wq, Wk, Wv, Wo, Wb, stats, xT);
    proj_kernel<<<1536, 256, 0, stream>>>(xT, Wb, q, k, vT);
    fattn_kernel<<<dim3(LL / 128, NB, S), 256, 0, stream>>>(q, k, vT, Op, l_s, iters);
    merge_kernel<<<(int)(elems / 8 / 256), 256, 0, stream>>>(Op, l_s, att, S);
    outm_kernel<<<dim3(LL / 128, CH / 64, NB), 256, 0, stream>>>(Wb, att, y, stats);
    bn_kernel<<<(NB * CH * LL / 8) / 256, 256, 0, stream>>>(x, y, stats, gamma, beta, out);
}

// Round 12
// 194.828 us; speedup vs baseline: 1.4042x; 1.0008x over previous
//
#include <hip/hip_runtime.h>
#include <cstdint>
#include <cstddef>

// Problem constants: N=4, C=D=256, H=W=64, L=4096
#define NB 4
#define CH 256
#define LL 4096

typedef unsigned short u16;
typedef unsigned int u32;
typedef unsigned char u8;
typedef __attribute__((ext_vector_type(8))) short bf16x8;
typedef __attribute__((ext_vector_type(4))) float f32x4;
typedef __attribute__((ext_vector_type(16))) float f32x16;

#define GPTR(p) ((const __attribute__((address_space(1))) u32*)(p))
#define LPTR(p) ((__attribute__((address_space(3))) u32*)(p))

__device__ __forceinline__ float blo(u32 x) { return __uint_as_float(x << 16); }
__device__ __forceinline__ float bhi(u32 x) { return __uint_as_float(x & 0xffff0000u); }
__device__ __forceinline__ float b2f(u16 h) { return __uint_as_float(((u32)h) << 16); }
__device__ __forceinline__ u16 f2b(float f) {
    u32 u = __float_as_uint(f);
    u32 r = (u + 0x7fffu + ((u >> 16) & 1u)) >> 16;  // RNE
    return (u16)r;
}
__device__ __forceinline__ u32 pack2(float a, float b) {
    return (u32)f2b(a) | ((u32)f2b(b) << 16);
}

// ---------------------------------------------------------------------------
// Kernel P: fused castw + tcast (R16, kept).
// ids [0,1024): tcast 64x64 tile; ids [1024,1280): castw + stats zero.
// ---------------------------------------------------------------------------
__global__ __launch_bounds__(256) void prep_kernel(
    const float* __restrict__ x, const float* __restrict__ Wq,
    const float* __restrict__ Wk, const float* __restrict__ Wv,
    const float* __restrict__ Wo, u16* __restrict__ Wb,
    float* __restrict__ stats, u16* __restrict__ xT) {
    const int id = blockIdx.x;
    const int tid = threadIdx.x;
    __shared__ u16 t[64][72];
    if (id < 1024) {
        // ---- tcast: x[n][c][l] f32 -> xT[n][l][c] bf16 ----
        const int n = id >> 8;
        const int c0 = ((id >> 6) & 3) * 64, l0 = (id & 63) * 64;
        const float* xs = x + (size_t)n * CH * LL;
        const int lq = (tid & 15) * 4, cc = tid >> 4;
#pragma unroll
        for (int p = 0; p < 4; ++p) {
            int c = cc + p * 16;
            float4 v = *(const float4*)&xs[(size_t)(c0 + c) * LL + l0 + lq];
            t[lq + 0][c] = f2b(v.x);
            t[lq + 1][c] = f2b(v.y);
            t[lq + 2][c] = f2b(v.z);
            t[lq + 3][c] = f2b(v.w);
        }
        __syncthreads();
        u16* xo = xT + (size_t)n * LL * CH;
        const int l = tid >> 2, c8 = (tid & 3) * 16;
#pragma unroll
        for (int h = 0; h < 2; ++h) {
            uint4 vv = *(uint4*)&t[l][c8 + h * 8];
            *(uint4*)&xo[(size_t)(l0 + l) * CH + c0 + c8 + h * 8] = vv;
        }
    } else {
        // ---- castw: weights f32 -> bf16 Wb[mat][d][c]; zero BN stats ----
        const int j = id - 1024;
        const int i = (j & 63) * 256 + tid;
        const int m = j >> 6;
        if (m == 0 && (j & 63) < 2) stats[i] = 0.0f;
        const float* src = (m == 0) ? Wq : (m == 1) ? Wk : (m == 2) ? Wv : Wo;
        float4 v = ((const float4*)src)[i];
        uint2 o;
        o.x = pack2(v.x, v.y);
        o.y = pack2(v.z, v.w);
        ((uint2*)(Wb + m * 65536))[i] = o;
    }
}

// ---------------------------------------------------------------------------
// Kernel 1: fused projqk + projv (R16, kept). LDS-staged B-operand.
// ids [0,1024): q/k projection; ids [1024,1536): v projection.
// ---------------------------------------------------------------------------
__global__ __launch_bounds__(256, 2) void proj_kernel(
    const u16* __restrict__ xT, const u16* __restrict__ Wb,
    u16* __restrict__ q, u16* __restrict__ k, u16* __restrict__ vT) {
    const int id = blockIdx.x;
    const int tid = threadIdx.x;
    const int w = tid >> 6, lane = tid & 63;
    const int lhi = lane >> 4, llo = lane & 15;

    __shared__ __align__(16) u16 Bs[128 * 256];  // 64 KB, chunk-XOR swizzled

    if (id < 1024) {
        // ---- projqk ----
        const int n = id >> 8;
        const int yy = (id >> 6) & 3;
        const int dhalf = yy & 1, mat = yy >> 1;
        const int l0 = (id & 63) * 64;
        const int d0 = dhalf * 128;

        const u16* xn = xT + (size_t)n * LL * CH;
        const u16* Wm = Wb + mat * 65536 + (size_t)d0 * CH;

#pragma unroll
        for (int i = 0; i < 16; ++i) {
            int s = i * 256 + tid;
            int r = s >> 5, c = s & 31;
            __builtin_amdgcn_global_load_lds(GPTR(Wm + r * CH + (c ^ (r & 31)) * 8),
                                             LPTR((char*)Bs + i * 4096 + w * 1024),
                                             16, 0, 0);
        }

        bf16x8 af[8];
        const u16* abase = xn + (size_t)(l0 + w * 16 + llo) * CH + lhi * 8;
#pragma unroll
        for (int ks = 0; ks < 8; ++ks) af[ks] = *(const bf16x8*)(abase + ks * 32);

        f32x4 acc[8];
#pragma unroll
        for (int t = 0; t < 8; ++t) acc[t] = (f32x4){0.f, 0.f, 0.f, 0.f};

        __syncthreads();

#pragma unroll
        for (int ks = 0; ks < 8; ++ks) {
#pragma unroll
            for (int ct = 0; ct < 8; ++ct) {
                const int rr = ct * 16 + llo;
                bf16x8 bf = *(const bf16x8*)(Bs + rr * CH +
                                             ((ks * 4 + lhi) ^ (rr & 31)) * 8);
                acc[ct] = __builtin_amdgcn_mfma_f32_16x16x32_bf16(af[ks], bf, acc[ct], 0, 0, 0);
            }
        }

        u16* o = (mat ? k : q) + (size_t)n * LL * CH;
#pragma unroll
        for (int r = 0; r < 4; ++r) {
            int lr = l0 + w * 16 + lhi * 4 + r;
#pragma unroll
            for (int ct = 0; ct < 8; ++ct)
                o[(size_t)lr * CH + d0 + ct * 16 + llo] = f2b(acc[ct][r]);
        }
    } else {
        // ---- projv ----
        const int j = id - 1024;
        const int n = j >> 7;
        const int d0 = ((j >> 5) & 3) * 64;
        const int l0 = (j & 31) * 128;

        const u16* xn = xT + (size_t)n * LL * CH + (size_t)l0 * CH;
        const u16* Wm = Wb + 2 * 65536;

#pragma unroll
        for (int i = 0; i < 16; ++i) {
            int s = i * 256 + tid;
            int r = s >> 5, c = s & 31;
            __builtin_amdgcn_global_load_lds(GPTR(xn + r * CH + (c ^ (r & 31)) * 8),
                                             LPTR((char*)Bs + i * 4096 + w * 1024),
                                             16, 0, 0);
        }

        bf16x8 af[8];
        const u16* abase = Wm + (size_t)(d0 + w * 16 + llo) * CH + lhi * 8;
#pragma unroll
        for (int ks = 0; ks < 8; ++ks) af[ks] = *(const bf16x8*)(abase + ks * 32);

        f32x4 acc[8];
#pragma unroll
        for (int t = 0; t < 8; ++t) acc[t] = (f32x4){0.f, 0.f, 0.f, 0.f};

        __syncthreads();

#pragma unroll
        for (int ks = 0; ks < 8; ++ks) {
#pragma unroll
            for (int ct = 0; ct < 8; ++ct) {
                const int rr = ct * 16 + llo;
                bf16x8 bf = *(const bf16x8*)(Bs + rr * CH +
                                             ((ks * 4 + lhi) ^ (rr & 31)) * 8);
                acc[ct] = __builtin_amdgcn_mfma_f32_16x16x32_bf16(af[ks], bf, acc[ct], 0, 0, 0);
            }
        }

        u16* o = vT + (size_t)n * CH * LL;
#pragma unroll
        for (int r = 0; r < 4; ++r) {
            int dr = d0 + w * 16 + lhi * 4 + r;
#pragma unroll
            for (int ct = 0; ct < 8; ++ct)
                o[(size_t)dr * LL + l0 + ct * 16 + llo] = f2b(acc[ct][r]);
        }
    }
}

// ---------------------------------------------------------------------------
// Kernel 2: bf16 flash attention (R22 = R19 + softmax/PV interleave).
// R11 audit (wall 5625 cyc/iter): QK/PV phases are LDS-issue bound (~1536
// each); softmax (~480 cyc) leaves BOTH LDS and matrix pipes idle in wave
// lockstep. R22 splits softmax: half-0 (g=0,1) -> pa[0] -> PV(sp=0, 8 MFMA)
// -> half-1 (g=2,3) -> pa[1] -> PV(sp=1). The sp=0 MFMAs overlap softmax
// half-1 on separate pipes. oacc accumulation order (sp0 then sp1) and lrun
// g-order UNCHANGED -> bit-identical output. Register-neutral (W half-live).
// Everything else identical to R19 (72.5 us, MfmaUtil 44, conflicts 0).
// ---------------------------------------------------------------------------
__global__ __launch_bounds__(256, 2) void fattn_kernel(
    const u16* __restrict__ q, const u16* __restrict__ k,
    const u16* __restrict__ vT, u16* __restrict__ Op, float* __restrict__ l_s,
    int iters) {
    const int n = blockIdx.y;
    const int s_id = blockIdx.z;
    const int l0 = blockIdx.x * 128;
    const int m_base = s_id * iters * 32;
    const int tid = threadIdx.x;
    const int w = tid >> 6;
    const int lane = tid & 63;
    const int l31 = lane & 31;
    const int h = lane >> 5;

    __shared__ __align__(16) char smem[65536];
    // K buffers @ 0 / 16384 ; V buffers @ 32768 / 49152

    // ---- Q fragments: lane holds Q[q=w*32+l31][c = s*16 + h*8 .. +8] ----
    bf16x8 qf[16];
    {
        const u16* base = q + (size_t)(n * LL + l0 + w * 32 + l31) * CH + h * 8;
#pragma unroll
        for (int s = 0; s < 16; ++s) qf[s] = *(const bf16x8*)(base + s * 16);
    }

    const u16* kg = k + (size_t)n * LL * CH;
    const u16* vg = vT + (size_t)n * CH * LL;

    // iter-invariant swizzled staging offsets (u16 elems); slot s = i*256+tid
    int okK[4], okV[4];
#pragma unroll
    for (int i = 0; i < 4; ++i) {
        int s = i * 256 + tid;
        int rK = s >> 5;
        int cK = (s & 31) ^ rK;
        okK[i] = rK * CH + cK * 8;
        int dV = s >> 2;
        int cV = (s & 3) ^ ((dV & 3) ^ ((dV >> 2) & 3));
        okV[i] = dV * LL + cV * 8;
    }

    f32x16 oacc[8];
#pragma unroll
    for (int t = 0; t < 8; ++t)
        oacc[t] = (f32x16){0.f, 0.f, 0.f, 0.f, 0.f, 0.f, 0.f, 0.f,
                           0.f, 0.f, 0.f, 0.f, 0.f, 0.f, 0.f, 0.f};
    float lrun = 0.f;

    const float C1 = 0.09016844005556021f;  // (1/16) * log2(e)
    const int kx = h ^ l31;                              // K read chunk XOR
    const int hg = h ^ ((lane & 3) ^ ((lane >> 2) & 3)); // V read chunk base

    // ---- prologue: issue tile 0 into buffer 0 ----
    {
        const u16* kg2 = kg + (size_t)m_base * CH;
        const u16* vg2 = vg + m_base;
#pragma unroll
        for (int i = 0; i < 4; ++i) {
            __builtin_amdgcn_global_load_lds(GPTR(kg2 + okK[i]),
                                             LPTR(smem + i * 4096 + w * 1024), 16, 0, 0);
            __builtin_amdgcn_global_load_lds(GPTR(vg2 + okV[i]),
                                             LPTR(smem + 32768 + i * 4096 + w * 1024),
                                             16, 0, 0);
        }
    }

    for (int it = 0; it < iters; ++it) {
        __syncthreads();
        if (it + 1 < iters) {
            const int m1 = m_base + (it + 1) * 32;
            const u16* kg2 = kg + (size_t)m1 * CH;
            const u16* vg2 = vg + m1;
            char* Kb = smem + ((it + 1) & 1) * 16384;
            char* Vb = smem + 32768 + ((it + 1) & 1) * 16384;
#pragma unroll
            for (int i = 0; i < 4; ++i) {
                __builtin_amdgcn_global_load_lds(GPTR(kg2 + okK[i]),
                                                 LPTR(Kb + i * 4096 + w * 1024), 16, 0, 0);
                __builtin_amdgcn_global_load_lds(GPTR(vg2 + okV[i]),
                                                 LPTR(Vb + i * 4096 + w * 1024), 16, 0, 0);
            }
        }
        const u16* Kl = (const u16*)(smem + (it & 1) * 16384);
        const u16* Vl = (const u16*)(smem + 32768 + (it & 1) * 16384);

        // ---- S^T = K*Q^T as one 32x32x16 chain over 16 c-steps ----
        f32x16 sacc = (f32x16){0.f, 0.f, 0.f, 0.f, 0.f, 0.f, 0.f, 0.f,
                               0.f, 0.f, 0.f, 0.f, 0.f, 0.f, 0.f, 0.f};
        __builtin_amdgcn_s_setprio(1);
#pragma unroll
        for (int s = 0; s < 16; ++s) {
            bf16x8 af = *(const bf16x8*)(Kl + l31 * 256 + ((2 * s) ^ kx) * 8);
            sacc = __builtin_amdgcn_mfma_f32_32x32x16_bf16(af, qf[s], sacc, 0, 0, 0);
        }
        __builtin_amdgcn_s_setprio(0);

        // ---- interleaved softmax + PV: half-0 -> pa0 -> PV(sp=0) overlaps
        // half-1 -> pa1 -> PV(sp=1). Same per-element math and identical
        // oacc/lrun accumulation order as R19. ----
        u32 W[4][2];
#pragma unroll
        for (int sp = 0; sp < 2; ++sp) {
#pragma unroll
            for (int g = 2 * sp; g < 2 * sp + 2; ++g) {
                float p0 = __builtin_amdgcn_exp2f(sacc[4 * g + 0] * C1);
                float p1 = __builtin_amdgcn_exp2f(sacc[4 * g + 1] * C1);
                float p2 = __builtin_amdgcn_exp2f(sacc[4 * g + 2] * C1);
                float p3 = __builtin_amdgcn_exp2f(sacc[4 * g + 3] * C1);
                lrun += (p0 + p1) + (p2 + p3);
                asm("v_cvt_pk_bf16_f32 %0, %1, %2" : "=v"(W[g][0]) : "v"(p0), "v"(p1));
                asm("v_cvt_pk_bf16_f32 %0, %1, %2" : "=v"(W[g][1]) : "v"(p2), "v"(p3));
            }
            // P->A-frag via permlane32_swap: word j = new vdst, word 2+j =
            // new vsrc of swap(vdst=W[2sp][j], vsrc=W[2sp+1][j]).
            u32 a0 = W[2 * sp][0], b0 = W[2 * sp + 1][0];
            asm("v_permlane32_swap_b32 %0, %1" : "+v"(a0), "+v"(b0));
            u32 a1 = W[2 * sp][1], b1 = W[2 * sp + 1][1];
            asm("v_permlane32_swap_b32 %0, %1" : "+v"(a1), "+v"(b1));
            union { u32 u[4]; bf16x8 v; } pk;
            pk.u[0] = a0;
            pk.u[1] = a1;
            pk.u[2] = b0;
            pk.u[3] = b1;
            bf16x8 pa = pk.v;

            // PV for this k-step: 8 d-tiles of 32x32x16
            __builtin_amdgcn_s_setprio(1);
#pragma unroll
            for (int dt = 0; dt < 8; ++dt) {
                bf16x8 vf = *(const bf16x8*)(Vl + (dt * 32 + l31) * 32 +
                                             ((2 * sp) ^ hg) * 8);
                oacc[dt] = __builtin_amdgcn_mfma_f32_32x32x16_bf16(pa, vf, oacc[dt], 0, 0, 0);
            }
            __builtin_amdgcn_s_setprio(0);
        }
    }

    // ---- epilogue: store un-normalized partial O (bf16) + l (fp32) ----
    u16* ap = Op + (size_t)((s_id * NB + n) * (size_t)LL + l0 + w * 32) * CH;
    float* lp = l_s + (size_t)s_id * NB * LL + (size_t)n * LL + l0 + w * 32;
    lrun += __shfl_xor(lrun, 32);
    if (h == 0) lp[l31] = lrun;
#pragma unroll
    for (int dt = 0; dt < 8; ++dt) {
#pragma unroll
        for (int r = 0; r < 16; ++r) {
            int qrow = (r & 3) + 8 * (r >> 2) + 4 * h;
            ap[(size_t)qrow * CH + dt * 32 + l31] = f2b(oacc[dt][r]);
        }
    }
}

// ---------------------------------------------------------------------------
// Kernel 2c: merge splits (R9 structure; R22 widened to 16 elems/thread --
// fewer, fatter blocks for this short ramp-bound streaming kernel).
// att[i] = (sum_s Op[s][i]) / (sum_s l_s[s][row])
// ---------------------------------------------------------------------------
__global__ __launch_bounds__(256) void merge_kernel(
    const u16* __restrict__ Op, const float* __restrict__ l_s,
    u16* __restrict__ att, int S) {
    const size_t t16 = (size_t)blockIdx.x * 256 + threadIdx.x;
    const size_t flat = t16 * 16;
    const size_t row = flat >> 8;  // 16 | 256 -> single row per thread-chunk
    float lsum = 0.0f;
    for (int s = 0; s < S; ++s) lsum += l_s[(size_t)s * NB * LL + row];
    const float inv = 1.0f / lsum;
    float acc[16];
#pragma unroll
    for (int j = 0; j < 16; ++j) acc[j] = 0.0f;
    for (int s = 0; s < S; ++s) {
        const u16* src = Op + (size_t)s * NB * LL * CH + flat;
        uint4 r0 = *(const uint4*)src;
        uint4 r1 = *(const uint4*)(src + 8);
        acc[0] += blo(r0.x);  acc[1] += bhi(r0.x);
        acc[2] += blo(r0.y);  acc[3] += bhi(r0.y);
        acc[4] += blo(r0.z);  acc[5] += bhi(r0.z);
        acc[6] += blo(r0.w);  acc[7] += bhi(r0.w);
        acc[8] += blo(r1.x);  acc[9] += bhi(r1.x);
        acc[10] += blo(r1.y); acc[11] += bhi(r1.y);
        acc[12] += blo(r1.z); acc[13] += bhi(r1.z);
        acc[14] += blo(r1.w); acc[15] += bhi(r1.w);
    }
    uint4 o0, o1;
    o0.x = pack2(acc[0] * inv, acc[1] * inv);
    o0.y = pack2(acc[2] * inv, acc[3] * inv);
    o0.z = pack2(acc[4] * inv, acc[5] * inv);
    o0.w = pack2(acc[6] * inv, acc[7] * inv);
    o1.x = pack2(acc[8] * inv, acc[9] * inv);
    o1.y = pack2(acc[10] * inv, acc[11] * inv);
    o1.z = pack2(acc[12] * inv, acc[13] * inv);
    o1.w = pack2(acc[14] * inv, acc[15] * inv);
    *(uint4*)(att + flat) = o0;
    *(uint4*)(att + flat + 8) = o1;
}

// ---------------------------------------------------------------------------
// Kernel 3: output projection via MFMA + fused BN partial sums. y bf16.
// B = att l-tile staged in LDS (R14 template; R9 form, frozen).
// ---------------------------------------------------------------------------
__global__ __launch_bounds__(256, 2) void outm_kernel(
    const u16* __restrict__ Wb, const u16* __restrict__ att,
    u16* __restrict__ y, float* __restrict__ stats) {
    const int n = blockIdx.z;
    const int o0 = blockIdx.y * 64;
    const int l0 = blockIdx.x * 128;
    const int tid = threadIdx.x;
    const int w = tid >> 6, lane = tid & 63;
    const int lhi = lane >> 4, llo = lane & 15;

    __shared__ __align__(16) u16 Bs[128 * 256];  // 64 KB

    const u16* an = att + (size_t)n * LL * CH + (size_t)l0 * CH;
    const u16* Wm = Wb + 3 * 65536;

#pragma unroll
    for (int i = 0; i < 16; ++i) {
        int s = i * 256 + tid;
        int r = s >> 5, c = s & 31;
        __builtin_amdgcn_global_load_lds(GPTR(an + r * CH + (c ^ (r & 31)) * 8),
                                         LPTR((char*)Bs + i * 4096 + w * 1024),
                                         16, 0, 0);
    }

    bf16x8 af[8];
    const u16* abase = Wm + (size_t)(o0 + w * 16 + llo) * CH + lhi * 8;
#pragma unroll
    for (int ks = 0; ks < 8; ++ks) af[ks] = *(const bf16x8*)(abase + ks * 32);

    f32x4 acc[8];
#pragma unroll
    for (int t = 0; t < 8; ++t) acc[t] = (f32x4){0.f, 0.f, 0.f, 0.f};

    __syncthreads();

#pragma unroll
    for (int ks = 0; ks < 8; ++ks) {
#pragma unroll
        for (int ct = 0; ct < 8; ++ct) {
            const int rr = ct * 16 + llo;
            bf16x8 bf = *(const bf16x8*)(Bs + rr * CH +
                                         ((ks * 4 + lhi) ^ (rr & 31)) * 8);
            acc[ct] = __builtin_amdgcn_mfma_f32_16x16x32_bf16(af[ks], bf, acc[ct], 0, 0, 0);
        }
    }

    u16* yn = y + (size_t)n * CH * LL;
#pragma unroll
    for (int r = 0; r < 4; ++r) {
        const int orow = o0 + w * 16 + lhi * 4 + r;
        float ts = 0.0f, tq = 0.0f;
#pragma unroll
        for (int ct = 0; ct < 8; ++ct) {
            float vv = acc[ct][r];
            yn[(size_t)orow * LL + l0 + ct * 16 + llo] = f2b(vv);
            ts += vv;
            tq += vv * vv;
        }
        ts += __shfl_xor(ts, 1); tq += __shfl_xor(tq, 1);
        ts += __shfl_xor(ts, 2); tq += __shfl_xor(tq, 2);
        ts += __shfl_xor(ts, 4); tq += __shfl_xor(tq, 4);
        ts += __shfl_xor(ts, 8); tq += __shfl_xor(tq, 8);
        if (llo == 0) {
            atomicAdd(&stats[orow], ts);
            atomicAdd(&stats[256 + orow], tq);
        }
    }
}

// ---------------------------------------------------------------------------
// Kernel 4: BN apply (batch stats, biased var) + residual. y read as bf16.
// R21 8-elem form (kept: +2.4 us vs 4-elem).
// ---------------------------------------------------------------------------
__global__ __launch_bounds__(256) void bn_kernel(
    const float* __restrict__ x, const u16* __restrict__ y,
    const float* __restrict__ stats, const float* __restrict__ gamma,
    const float* __restrict__ beta, float* __restrict__ out) {
    const int idx = blockIdx.x * 256 + threadIdx.x;  // per 8 elems
    const int base = idx * 8;
    const int c = (base >> 12) & 255;  // (base / L) % C
    const float cnt = 1.0f / 16384.0f; // N*L
    float mean = stats[c] * cnt;
    float var = stats[256 + c] * cnt - mean * mean;
    float rstd = rsqrtf(var + 1e-4f);
    float g = gamma[c] * rstd;
    float b = beta[c];
    uint4 yv = ((const uint4*)y)[idx];
    float4 xv0 = ((const float4*)x)[idx * 2];
    float4 xv1 = ((const float4*)x)[idx * 2 + 1];
    float4 o0, o1;
    o0.x = xv0.x + (blo(yv.x) - mean) * g + b;
    o0.y = xv0.y + (bhi(yv.x) - mean) * g + b;
    o0.z = xv0.z + (blo(yv.y) - mean) * g + b;
    o0.w = xv0.w + (bhi(yv.y) - mean) * g + b;
    o1.x = xv1.x + (blo(yv.z) - mean) * g + b;
    o1.y = xv1.y + (bhi(yv.z) - mean) * g + b;
    o1.z = xv1.z + (blo(yv.w) - mean) * g + b;
    o1.w = xv1.w + (bhi(yv.w) - mean) * g + b;
    ((float4*)out)[idx * 2] = o0;
    ((float4*)out)[idx * 2 + 1] = o1;
}

// ---------------------------------------------------------------------------
extern "C" void kernel_launch(void* const* d_in, const int* in_sizes, int n_in,
                              void* d_out, int out_size, void* d_ws, size_t ws_size,
                              hipStream_t stream) {
    const float* x = (const float*)d_in[0];
    const float* Wq = (const float*)d_in[1];
    const float* Wk = (const float*)d_in[2];
    const float* Wv = (const float*)d_in[3];
    const float* Wo = (const float*)d_in[4];
    const float* gamma = (const float*)d_in[5];
    const float* beta = (const float*)d_in[6];
    float* out = (float*)d_out;

    const size_t elems = (size_t)NB * LL * CH;  // 4,194,304

    // pick largest split count whose workspace fits (S=4 needs ~59.4 MB)
    int S = 1;
    for (int cand = 4; cand >= 2; cand >>= 1) {
        size_t need = elems * 2 * (size_t)(3 + cand) +
                      (size_t)cand * NB * LL * 4 + 524288 + 8192;
        if (ws_size >= need) { S = cand; break; }
    }
    const int iters = 128 / S;

    char* wsb = (char*)d_ws;
    u16* q = (u16*)wsb;                             // 8.39 MB (bf16)
    u16* k = q + elems;                             // 8.39 MB (bf16)
    u16* vT = k + elems;                            // 8.39 MB (bf16)
    u16* Op = vT + elems;                           // S * 8.39 MB (bf16)
    u16* xT = Op;                                   // overlay: dead before fattn
    float* l_s = (float*)(Op + (size_t)S * elems);  // S * 64 KB
    u16* Wb = (u16*)(l_s + (size_t)S * NB * LL);    // 512 KB
    float* stats = (float*)(Wb + 4 * 65536);        // 2 KB
    u16* att = q;   // overlay q (dead after fattn)
    u16* y = k;     // overlay k (dead after merge)

    prep_kernel<<<1280, 256, 0, stream>>>(x, Wq, Wk, Wv, Wo, Wb, stats, xT);
    proj_kernel<<<1536, 256, 0, stream>>>(xT, Wb, q, k, vT);
    fattn_kernel<<<dim3(LL / 128, NB, S), 256, 0, stream>>>(q, k, vT, Op, l_s, iters);
    merge_kernel<<<(int)(elems / 16 / 256), 256, 0, stream>>>(Op, l_s, att, S);
    outm_kernel<<<dim3(LL / 128, CH / 64, NB), 256, 0, stream>>>(Wb, att, y, stats);
    bn_kernel<<<(NB * CH * LL / 8) / 256, 256, 0, stream>>>(x, y, stats, gamma, beta, out);
}